// Round 15
// baseline (79.358 us; speedup 1.0000x reference)
//
#include <hip/hip_runtime.h>
#include <cstdint>
#include <cstddef>

typedef float  f32x4  __attribute__((ext_vector_type(4)));
typedef long long i64;
typedef unsigned char uchar;

#define N_ROWS 8192
#define KDIM   256
#define TEMP_INV 2.0f
#define LOG2E  1.4426950408889634f
#define EXPC   (TEMP_INV * LOG2E)

#define AS1 __attribute__((address_space(1)))
#define AS3 __attribute__((address_space(3)))

// ---------------- Kernel 1: fused prep ----------------
// Blocks 0..2047: normalize+fp8-cast rows UNPERMUTED. Block 2048: build perm
// (coalesced label reads; any within-class order is a valid permutation).
__global__ __launch_bounds__(256) void prep(const float* __restrict__ logits,
        const int* __restrict__ label, uchar* __restrict__ xn8,
        int* __restrict__ perm, int* __restrict__ labelPerm,
        int* __restrict__ classStart, int* __restrict__ cumTiles)
{
    __shared__ int lcnt[256][10];
    __shared__ int cstart[11];
    __shared__ int ccount[10];
    const int tid = threadIdx.x;
    const int bid = blockIdx.x;

    if (bid < 2048) {   // normalize path (no perm dependency)
        const int p = bid * 4 + (tid >> 6);
        const int lane = tid & 63;
        float4 v = reinterpret_cast<const float4*>(logits + (size_t)p * KDIM)[lane];
        float ss = v.x*v.x + v.y*v.y + v.z*v.z + v.w*v.w;
        #pragma unroll
        for (int off = 32; off >= 1; off >>= 1) ss += __shfl_xor(ss, off, 64);
        float inv = 1.0f / fmaxf(sqrtf(ss), 1e-8f);
        int pk = __builtin_amdgcn_cvt_pk_fp8_f32(v.x * inv, v.y * inv, 0, false);
        pk     = __builtin_amdgcn_cvt_pk_fp8_f32(v.z * inv, v.w * inv, pk, true);
        reinterpret_cast<unsigned int*>(xn8 + (size_t)p * KDIM)[lane] = (unsigned int)pk;
        return;
    }

    // ---- permutation build (one block, coalesced reads) ----
    const int wave = tid >> 6, lane = tid & 63;
    int lab[32];
    #pragma unroll
    for (int j = 0; j < 32; ++j) {
        int c = label[tid + j * 256];
        lab[j] = (c < 0) ? 0 : (c > 9 ? 9 : c);
    }
    int loc[10] = {0,0,0,0,0,0,0,0,0,0};
    #pragma unroll
    for (int j = 0; j < 32; ++j) loc[lab[j]]++;
    #pragma unroll
    for (int c = 0; c < 10; ++c) lcnt[tid][c] = loc[c];
    __syncthreads();

    for (int c = wave; c < 10; c += 4) {
        int s0 = lcnt[lane*4+0][c], s1 = lcnt[lane*4+1][c];
        int s2 = lcnt[lane*4+2][c], s3 = lcnt[lane*4+3][c];
        int tot = s0 + s1 + s2 + s3;
        int incl = tot;
        #pragma unroll
        for (int d = 1; d < 64; d <<= 1) {
            int up = __shfl_up(incl, d, 64);
            if (lane >= d) incl += up;
        }
        int excl = incl - tot;
        lcnt[lane*4+0][c] = excl;
        lcnt[lane*4+1][c] = excl + s0;
        lcnt[lane*4+2][c] = excl + s0 + s1;
        lcnt[lane*4+3][c] = excl + s0 + s1 + s2;
        if (lane == 63) ccount[c] = incl;
    }
    __syncthreads();

    if (tid == 0) {
        int run = 0, runT = 0;
        for (int c = 0; c < 10; ++c) {
            cstart[c] = run; classStart[c] = run;
            int tpc = (ccount[c] + 127) >> 7;
            cumTiles[c] = runT;
            run  += ccount[c];
            runT += tpc * (tpc + 1) / 2;     // upper-tri within class
        }
        cstart[10] = run; classStart[10] = run; cumTiles[10] = runT;
    }
    __syncthreads();

    int ofs[10];
    #pragma unroll
    for (int c = 0; c < 10; ++c) ofs[c] = lcnt[tid][c];
    #pragma unroll
    for (int j = 0; j < 32; ++j) {
        int c = lab[j];
        int pos = cstart[c] + ofs[c]++;
        perm[pos] = tid + j * 256;
        labelPerm[pos] = c;
    }
}

// ================= fp8 one-shot 128x128 core pieces (R11-validated) =========
// LDS per matrix: 128 rows x 256 B. Stored 16B-chunk slot = c ^ (row&15).
// Rule #21: linear LDS dest, pre-swizzled GLOBAL source, same XOR on ds_read.
__device__ __forceinline__ void stage_mat(const uchar* __restrict__ xn8,
        const int* __restrict__ perm, int base, uchar* dst, int tid)
{
    const int t4 = tid >> 4;
    const int ch = (tid & 15) ^ t4;          // logical chunk, constant per thread
    #pragma unroll
    for (int i = 0; i < 8; ++i) {
        const int row = i * 16 + t4;         // row&15 == t4 for all i
        const int lds_off = (i * 256 + tid) * 16;   // wave-uniform base + lane*16
        const uchar* g = xn8 + (size_t)perm[base + row] * KDIM + ch * 16;
        __builtin_amdgcn_global_load_lds((const AS1 void*)g, (AS3 void*)(dst + lds_off), 16, 0, 0);
    }
}

__device__ __forceinline__ void mfma_oneshot(const uchar* As, const uchar* Bs,
        f32x4 (&acc)[4][4], int wave, int lane)
{
    const int wr = wave >> 1, wc = wave & 1;
    const int lrow = lane & 15, kgrp = lane >> 4;
    const int ch2 = kgrp >> 1, half8 = (kgrp & 1) * 8;
    #pragma unroll
    for (int s = 0; s < 8; ++s) {
        const int c16 = s * 2 + ch2;         // logical 16B chunk for this K=32 step
        i64 a[4], b[4];
        #pragma unroll
        for (int mi = 0; mi < 4; ++mi) {
            const int row = wr*64 + mi*16 + lrow;
            a[mi] = *reinterpret_cast<const i64*>(As + (size_t)row * 256 + ((c16 ^ lrow) * 16) + half8);
        }
        #pragma unroll
        for (int ni = 0; ni < 4; ++ni) {
            const int row = wc*64 + ni*16 + lrow;
            b[ni] = *reinterpret_cast<const i64*>(Bs + (size_t)row * 256 + ((c16 ^ lrow) * 16) + half8);
        }
        #pragma unroll
        for (int mi = 0; mi < 4; ++mi)
            #pragma unroll
            for (int ni = 0; ni < 4; ++ni)
                acc[mi][ni] = __builtin_amdgcn_mfma_f32_16x16x32_fp8_fp8(a[mi], b[ni], acc[mi][ni], 0, 0, 0);
    }
}

// Register-only epilogue: exp2 + diff-label mask, shfl_xor reduces, write tiny
// half-buffers. Uses NO large LDS -> runs concurrently with B1 staging.
__device__ __forceinline__ void epilogue_reg(f32x4 (&acc)[4][4],
        const int* labR, const int* labC, float (*rowHalf)[2], float (*colHalf)[2],
        int wave, int lane)
{
    const int wr = wave >> 1, wc = wave & 1;
    const int lrow = lane & 15, lgrp = lane >> 4;
    float colAcc[4] = {0.f, 0.f, 0.f, 0.f};
    #pragma unroll
    for (int mi = 0; mi < 4; ++mi) {
        #pragma unroll
        for (int reg = 0; reg < 4; ++reg) {
            const int tr = wr * 64 + mi * 16 + lgrp * 4 + reg;
            const int rl = labR[tr];
            float rowAcc = 0.f;
            #pragma unroll
            for (int ni = 0; ni < 4; ++ni) {
                const int tc = wc * 64 + ni * 16 + lrow;
                float e = __builtin_amdgcn_exp2f(acc[mi][ni][reg] * EXPC);
                float ed = (rl != labC[tc]) ? e : 0.f;
                rowAcc += ed;
                colAcc[ni] += ed;
            }
            #pragma unroll
            for (int off = 1; off < 16; off <<= 1)
                rowAcc += __shfl_xor(rowAcc, off, 64);
            if (lrow == 0) rowHalf[tr][wc] = rowAcc;
        }
    }
    #pragma unroll
    for (int ni = 0; ni < 4; ++ni) {
        colAcc[ni] += __shfl_xor(colAcc[ni], 16, 64);
        colAcc[ni] += __shfl_xor(colAcc[ni], 32, 64);
        if (lgrp == 0) colHalf[wc * 64 + ni * 16 + lrow][wr] = colAcc[ni];
    }
}

// ---------------- Kernel 2: paired upper-tri tiles (bi,bj0),(bi,bj0+1) -----
// A-panel staged once per pair; B1 drain hidden under epilogue0.
__global__ __launch_bounds__(256, 2) void phase1_gemm(const uchar* __restrict__ xn8,
        const int* __restrict__ perm, const int* __restrict__ labelPerm,
        float* __restrict__ pD)
{
    __shared__ __align__(16) uchar As[32768];
    __shared__ __align__(16) uchar Bs[32768];
    __shared__ float rowHalf[128][2];
    __shared__ float colHalf[128][2];
    __shared__ int labAll[384];   // [0:128) row, [128:256) col0, [256:384) col1

    const int tid = threadIdx.x;
    const int wave = tid >> 6, lane = tid & 63;

    // decode pair index -> (bi, bj0); np(bi) = ceil((64-bi)/2)
    int t = blockIdx.x, bi = 0;
    while (t >= ((65 - bi) >> 1)) { t -= (65 - bi) >> 1; ++bi; }
    const int bj0 = bi + 2 * t;
    const bool hasT1 = (bj0 + 1) < 64;
    const int bj1 = hasT1 ? (bj0 + 1) : bj0;
    const int rowBase = bi * 128, colBase0 = bj0 * 128, colBase1 = bj1 * 128;
    const bool isDiag0 = (bi == bj0);

    // class-sorted: whole subtile same class -> contributes 0 to D
    const int rl0 = labelPerm[rowBase];
    const bool same0 = (rl0 == labelPerm[colBase0 + 127]);
    const bool same1 = !hasT1 || (rl0 == labelPerm[colBase1 + 127]);

    if (same0 && same1) {   // all-zero pair: direct writes, no staging
        if (tid < 128) {
            pD[(size_t)bj0 * N_ROWS + rowBase + tid] = 0.f;
            if (hasT1) pD[(size_t)bj1 * N_ROWS + rowBase + tid] = 0.f;
        } else {
            if (!isDiag0) pD[(size_t)bi * N_ROWS + colBase0 + tid - 128] = 0.f;
            if (hasT1)    pD[(size_t)bi * N_ROWS + colBase1 + tid - 128] = 0.f;
        }
        return;
    }

    stage_mat(xn8, perm, rowBase, As, tid);                 // A once per pair
    if (!same0) stage_mat(xn8, perm, colBase0, Bs, tid);
    labAll[tid] = labelPerm[(tid < 128) ? (rowBase + tid) : (colBase0 + tid - 128)];
    if (tid < 128) labAll[256 + tid] = labelPerm[colBase1 + tid];
    __syncthreads();                                        // drain A (+B0)

    f32x4 acc[4][4] = {};
    if (!same0) mfma_oneshot(As, Bs, acc, wave, lane);
    __syncthreads();                                        // Bs reads complete

    if (hasT1 && !same1) stage_mat(xn8, perm, colBase1, Bs, tid);   // issue B1
    if (!same0)
        epilogue_reg(acc, labAll, labAll + 128, rowHalf, colHalf, wave, lane);
    __syncthreads();                                        // B1 drained + halves ready

    if (tid < 128)
        pD[(size_t)bj0 * N_ROWS + rowBase + tid] =
            same0 ? 0.f : (rowHalf[tid][0] + rowHalf[tid][1]);
    else if (!isDiag0)
        pD[(size_t)bi * N_ROWS + colBase0 + tid - 128] =
            same0 ? 0.f : (colHalf[tid - 128][0] + colHalf[tid - 128][1]);

    if (!hasT1) return;

    f32x4 acc1[4][4] = {};
    if (!same1) mfma_oneshot(As, Bs, acc1, wave, lane);
    __syncthreads();                                        // combine(t0) reads done
    if (!same1)
        epilogue_reg(acc1, labAll, labAll + 256, rowHalf, colHalf, wave, lane);
    __syncthreads();

    if (tid < 128)
        pD[(size_t)bj1 * N_ROWS + rowBase + tid] =
            same1 ? 0.f : (rowHalf[tid][0] + rowHalf[tid][1]);
    else   // bj1 > bi always -> never diagonal
        pD[(size_t)bi * N_ROWS + colBase1 + tid - 128] =
            same1 ? 0.f : (colHalf[tid - 128][0] + colHalf[tid - 128][1]);
}

// ---------------- Kernel 3: same-class upper-tri tiles (R11 one-shot) -------
__device__ __forceinline__ void stage_oneshot(const uchar* __restrict__ xn8,
        const int* __restrict__ perm, int rowBase, int colBase,
        uchar* As, uchar* Bs, int tid)
{
    const int t4 = tid >> 4;
    const int ch = (tid & 15) ^ t4;
    #pragma unroll
    for (int i = 0; i < 8; ++i) {
        const int row = i * 16 + t4;
        int rA = rowBase + row; if (rA > N_ROWS - 1) rA = N_ROWS - 1;
        int rB = colBase + row; if (rB > N_ROWS - 1) rB = N_ROWS - 1;
        const int lds_off = (i * 256 + tid) * 16;
        const uchar* gA = xn8 + (size_t)perm[rA] * KDIM + ch * 16;
        const uchar* gB = xn8 + (size_t)perm[rB] * KDIM + ch * 16;
        __builtin_amdgcn_global_load_lds((const AS1 void*)gA, (AS3 void*)(As + lds_off), 16, 0, 0);
        __builtin_amdgcn_global_load_lds((const AS1 void*)gB, (AS3 void*)(Bs + lds_off), 16, 0, 0);
    }
}

__global__ __launch_bounds__(256, 2) void phase3_loss(const uchar* __restrict__ xn8,
        const int* __restrict__ perm, const float* __restrict__ pD,
        const int* __restrict__ classStart, const int* __restrict__ cumTiles,
        float* __restrict__ partial)
{
    __shared__ __align__(16) char pool[65536];
    uchar* As = (uchar*)(pool);
    uchar* Bs = (uchar*)(pool + 32768);
    __shared__ float redF[256];
    __shared__ float DarrH[256];
    __shared__ float DarrR[128];
    __shared__ float DarrC[128];
    __shared__ int   meta[22];

    const int tid = threadIdx.x;
    const int wave = tid >> 6, lane = tid & 63;

    if (tid < 11) { meta[tid] = classStart[tid]; meta[11 + tid] = cumTiles[tid]; }
    __syncthreads();
    const int nTiles = meta[11 + 10];

    float tileSum = 0.f;
    for (int b = blockIdx.x; b < nTiles; b += 512) {
        __syncthreads();   // close previous iteration's LDS use

        int c = 0;
        while (c < 9 && b >= meta[11 + c + 1]) ++c;
        const int s = meta[c], e = meta[c + 1];
        const int nc = e - s;
        const int tps = (nc + 127) >> 7;
        int lt = b - meta[11 + c];
        int ti = 0;
        while (lt >= tps - ti) { lt -= tps - ti; ++ti; }
        const int tj = ti + lt;
        const bool isDiagT = (ti == tj);
        const int rowBase = s + ti * 128, colBase = s + tj * 128;

        // issue tile staging FIRST; latency hides under the gathers
        stage_oneshot(xn8, perm, rowBase, colBase, As, Bs, tid);

        // Darr gather (fixed order)
        {
            int r = rowBase + (tid & 127); if (r > N_ROWS - 1) r = N_ROWS - 1;
            const int half = tid >> 7;
            float d = 0.f;
            #pragma unroll 4
            for (int sl = half * 32; sl < half * 32 + 32; ++sl)
                d += pD[(size_t)sl * N_ROWS + r];
            DarrH[(tid & 127) * 2 + half] = d;
        }
        __syncthreads();
        if (tid < 128) DarrR[tid] = DarrH[tid * 2] + DarrH[tid * 2 + 1];
        __syncthreads();
        if (!isDiagT) {
            int r = colBase + (tid & 127); if (r > N_ROWS - 1) r = N_ROWS - 1;
            const int half = tid >> 7;
            float d = 0.f;
            #pragma unroll 4
            for (int sl = half * 32; sl < half * 32 + 32; ++sl)
                d += pD[(size_t)sl * N_ROWS + r];
            DarrH[(tid & 127) * 2 + half] = d;
            __syncthreads();
            if (tid < 128) DarrC[tid] = DarrH[tid * 2] + DarrH[tid * 2 + 1];
        }
        __syncthreads();   // staging + gathers all complete

        f32x4 acc[4][4] = {};
        mfma_oneshot(As, Bs, acc, wave, lane);

        const int wr = wave >> 1, wc = wave & 1;
        const int lrow = lane & 15, lgrp = lane >> 4;
        #pragma unroll
        for (int mi = 0; mi < 4; ++mi) {
            #pragma unroll
            for (int reg = 0; reg < 4; ++reg) {
                const int tr = wr * 64 + mi * 16 + lgrp * 4 + reg;
                const int r = rowBase + tr;
                if (r < e) {
                    const float Dr = DarrR[tr];
                    #pragma unroll
                    for (int ni = 0; ni < 4; ++ni) {
                        const int tc = wc * 64 + ni * 16 + lrow;
                        const int cg = colBase + tc;
                        if (cg < e) {
                            float sim = acc[mi][ni][reg];
                            float ev = __builtin_amdgcn_exp2f(sim * EXPC);
                            if (isDiagT) {
                                if (cg != r)
                                    tileSum += __logf(ev + Dr) - TEMP_INV * sim;
                            } else {
                                tileSum += __logf(ev + Dr) + __logf(ev + DarrC[tc])
                                         - 2.0f * TEMP_INV * sim;
                            }
                        }
                    }
                }
            }
        }
    }

    __syncthreads();
    redF[tid] = tileSum;
    __syncthreads();
    for (int st = 128; st > 0; st >>= 1) {
        if (tid < st) redF[tid] += redF[tid + st];
        __syncthreads();
    }
    if (tid == 0) partial[blockIdx.x] = redF[0];
}

// ---------------- Kernel 4: deterministic final reduction + scale ----------
__global__ void phase4_final(const float* __restrict__ partial, float* __restrict__ out)
{
    __shared__ float red[256];
    const int tid = threadIdx.x;
    float s = partial[tid] + partial[tid + 256];
    red[tid] = s;
    __syncthreads();
    for (int st = 128; st > 0; st >>= 1) {
        if (tid < st) red[tid] += red[tid + st];
        __syncthreads();
    }
    if (tid == 0) out[0] = red[0] * (1.0f / 16384.0f);
}

extern "C" void kernel_launch(void* const* d_in, const int* in_sizes, int n_in,
                              void* d_out, int out_size, void* d_ws, size_t ws_size,
                              hipStream_t stream)
{
    const float* logits = (const float*)d_in[0];
    const int*   label  = (const int*)d_in[1];
    float* out = (float*)d_out;

    char* ws = (char*)d_ws;
    uchar*  xn8       = (uchar*)(ws);                           // 2 MB
    float*  pD        = (float*)(ws + (2u << 20));              // 2 MB
    int*    perm      = (int*)(ws + (4u << 20));                // 32 KB
    int*    labelPerm = (int*)(ws + (4u << 20) + (32u << 10));  // 32 KB
    int*    classStart= (int*)(ws + (4u << 20) + (64u << 10));  // 64 B
    int*    cumTiles  = (int*)(ws + (4u << 20) + (64u << 10) + 256); // 64 B
    float*  partial   = (float*)(ws + (4u << 20) + (128u << 10));    // 2 KB

    hipLaunchKernelGGL(prep, dim3(2049), dim3(256), 0, stream,
                       logits, label, xn8, perm, labelPerm, classStart, cumTiles);
    hipLaunchKernelGGL(phase1_gemm, dim3(1056), dim3(256), 0, stream,
                       xn8, perm, labelPerm, pD);
    hipLaunchKernelGGL(phase3_loss, dim3(512), dim3(256), 0, stream,
                       xn8, perm, pD, classStart, cumTiles, partial);
    hipLaunchKernelGGL(phase4_final, dim3(1), dim3(256), 0, stream,
                       partial, out);
}

// Round 16
// 76.352 us; speedup vs baseline: 1.0394x; 1.0394x over previous
//
#include <hip/hip_runtime.h>
#include <cstdint>
#include <cstddef>

typedef float  f32x4  __attribute__((ext_vector_type(4)));
typedef long long i64;
typedef unsigned char uchar;

#define N_ROWS 8192
#define KDIM   256
#define TEMP_INV 2.0f
#define LOG2E  1.4426950408889634f
#define EXPC   (TEMP_INV * LOG2E)

#define AS1 __attribute__((address_space(1)))
#define AS3 __attribute__((address_space(3)))

// ---------------- Kernel 1: fused prep (R15-validated) ----------------
__global__ __launch_bounds__(256) void prep(const float* __restrict__ logits,
        const int* __restrict__ label, uchar* __restrict__ xn8,
        int* __restrict__ perm, int* __restrict__ labelPerm,
        int* __restrict__ classStart, int* __restrict__ cumTiles)
{
    __shared__ int lcnt[256][10];
    __shared__ int cstart[11];
    __shared__ int ccount[10];
    const int tid = threadIdx.x;
    const int bid = blockIdx.x;

    if (bid < 2048) {   // normalize path (no perm dependency)
        const int p = bid * 4 + (tid >> 6);
        const int lane = tid & 63;
        float4 v = reinterpret_cast<const float4*>(logits + (size_t)p * KDIM)[lane];
        float ss = v.x*v.x + v.y*v.y + v.z*v.z + v.w*v.w;
        #pragma unroll
        for (int off = 32; off >= 1; off >>= 1) ss += __shfl_xor(ss, off, 64);
        float inv = 1.0f / fmaxf(sqrtf(ss), 1e-8f);
        int pk = __builtin_amdgcn_cvt_pk_fp8_f32(v.x * inv, v.y * inv, 0, false);
        pk     = __builtin_amdgcn_cvt_pk_fp8_f32(v.z * inv, v.w * inv, pk, true);
        reinterpret_cast<unsigned int*>(xn8 + (size_t)p * KDIM)[lane] = (unsigned int)pk;
        return;
    }

    // ---- permutation build (one block, coalesced reads) ----
    const int wave = tid >> 6, lane = tid & 63;
    int lab[32];
    #pragma unroll
    for (int j = 0; j < 32; ++j) {
        int c = label[tid + j * 256];
        lab[j] = (c < 0) ? 0 : (c > 9 ? 9 : c);
    }
    int loc[10] = {0,0,0,0,0,0,0,0,0,0};
    #pragma unroll
    for (int j = 0; j < 32; ++j) loc[lab[j]]++;
    #pragma unroll
    for (int c = 0; c < 10; ++c) lcnt[tid][c] = loc[c];
    __syncthreads();

    for (int c = wave; c < 10; c += 4) {
        int s0 = lcnt[lane*4+0][c], s1 = lcnt[lane*4+1][c];
        int s2 = lcnt[lane*4+2][c], s3 = lcnt[lane*4+3][c];
        int tot = s0 + s1 + s2 + s3;
        int incl = tot;
        #pragma unroll
        for (int d = 1; d < 64; d <<= 1) {
            int up = __shfl_up(incl, d, 64);
            if (lane >= d) incl += up;
        }
        int excl = incl - tot;
        lcnt[lane*4+0][c] = excl;
        lcnt[lane*4+1][c] = excl + s0;
        lcnt[lane*4+2][c] = excl + s0 + s1;
        lcnt[lane*4+3][c] = excl + s0 + s1 + s2;
        if (lane == 63) ccount[c] = incl;
    }
    __syncthreads();

    if (tid == 0) {
        int run = 0, runT = 0;
        for (int c = 0; c < 10; ++c) {
            cstart[c] = run; classStart[c] = run;
            int tpc = (ccount[c] + 127) >> 7;
            cumTiles[c] = runT;
            run  += ccount[c];
            runT += tpc * (tpc + 1) / 2;     // upper-tri within class
        }
        cstart[10] = run; classStart[10] = run; cumTiles[10] = runT;
    }
    __syncthreads();

    int ofs[10];
    #pragma unroll
    for (int c = 0; c < 10; ++c) ofs[c] = lcnt[tid][c];
    #pragma unroll
    for (int j = 0; j < 32; ++j) {
        int c = lab[j];
        int pos = cstart[c] + ofs[c]++;
        perm[pos] = tid + j * 256;
        labelPerm[pos] = c;
    }
}

// ---------------- Kernel 2: upper-tri 128-tiles, 8-wave one-shot ------------
// LDS per matrix: 128 rows x 256 B. Stored 16B-chunk slot = c ^ (row&15).
// Rule #21: linear LDS dest, pre-swizzled GLOBAL source, same XOR on ds_read.
// 512 thr / 8 waves (2M x 4N), 2 blocks/CU -> 16 waves/CU (2x R11's).
__global__ __launch_bounds__(512, 4) void phase1_gemm(const uchar* __restrict__ xn8,
        const int* __restrict__ perm, const int* __restrict__ labelPerm,
        float* __restrict__ pD)
{
    __shared__ __align__(16) char pool[65536];
    uchar* As = (uchar*)(pool);
    uchar* Bs = (uchar*)(pool + 32768);
    float* rowD = (float*)pool;            // [128][4], aliases As post-release
    float* colD = (float*)(pool + 32768);  // [128][2], aliases Bs
    __shared__ int labLDS[256];

    const int tid = threadIdx.x;
    const int wave = tid >> 6, lane = tid & 63;

    int t = blockIdx.x, bi = 0;
    while (t >= 64 - bi) { t -= 64 - bi; ++bi; }
    const int bj = bi + t;
    const bool isDiag = (bi == bj);
    const int rowBase = bi * 128, colBase = bj * 128;

    // class-sorted rows: whole tile same class -> contributes 0 to D
    if (labelPerm[rowBase] == labelPerm[colBase + 127]) {
        if (tid < 128)                    pD[(size_t)bj * N_ROWS + rowBase + tid] = 0.f;
        else if (tid < 256 && !isDiag)    pD[(size_t)bi * N_ROWS + colBase + tid - 128] = 0.f;
        return;
    }

    // stage both 32-KB tiles: 2048 chunks each, 4 per thread per matrix
    {
        const int t4 = (tid >> 4) & 15;
        const int ch = (tid & 15) ^ t4;       // logical chunk, constant per thread
        #pragma unroll
        for (int i = 0; i < 4; ++i) {
            const int ci = i * 512 + tid;     // chunk index; (ci>>4)&15 == t4
            const int row = ci >> 4;
            const int lds_off = ci * 16;      // wave-uniform base + lane*16
            const uchar* gA = xn8 + (size_t)perm[rowBase + row] * KDIM + ch * 16;
            const uchar* gB = xn8 + (size_t)perm[colBase + row] * KDIM + ch * 16;
            __builtin_amdgcn_global_load_lds((const AS1 void*)gA, (AS3 void*)(As + lds_off), 16, 0, 0);
            __builtin_amdgcn_global_load_lds((const AS1 void*)gB, (AS3 void*)(Bs + lds_off), 16, 0, 0);
        }
    }
    if (tid < 256)
        labLDS[tid] = labelPerm[(tid < 128) ? (rowBase + tid) : (colBase + tid - 128)];
    __syncthreads();                          // one drain

    // ---- MFMA: wave (wr,wc) owns 64x32 output = acc[4][2] ----
    const int wr = wave >> 2, wc = wave & 3;
    const int lrow = lane & 15, kgrp = lane >> 4;
    const int ch2 = kgrp >> 1, half8 = (kgrp & 1) * 8;
    f32x4 acc[4][2] = {};
    #pragma unroll
    for (int s = 0; s < 8; ++s) {
        const int c16 = s * 2 + ch2;          // logical 16B chunk for this K=32 step
        i64 a[4], b[2];
        #pragma unroll
        for (int mi = 0; mi < 4; ++mi) {
            const int row = wr*64 + mi*16 + lrow;
            a[mi] = *reinterpret_cast<const i64*>(As + (size_t)row * 256 + ((c16 ^ lrow) * 16) + half8);
        }
        #pragma unroll
        for (int ni = 0; ni < 2; ++ni) {
            const int row = wc*32 + ni*16 + lrow;
            b[ni] = *reinterpret_cast<const i64*>(Bs + (size_t)row * 256 + ((c16 ^ lrow) * 16) + half8);
        }
        #pragma unroll
        for (int mi = 0; mi < 4; ++mi)
            #pragma unroll
            for (int ni = 0; ni < 2; ++ni)
                acc[mi][ni] = __builtin_amdgcn_mfma_f32_16x16x32_fp8_fp8(a[mi], b[ni], acc[mi][ni], 0, 0, 0);
    }
    __syncthreads();                          // release LDS for rowD/colD

    // ---- register epilogue: exp2 + diff-label mask, shfl reduces ----
    const int lgrp = lane >> 4;
    float colAcc[2] = {0.f, 0.f};
    #pragma unroll
    for (int mi = 0; mi < 4; ++mi) {
        #pragma unroll
        for (int reg = 0; reg < 4; ++reg) {
            const int tr = wr * 64 + mi * 16 + lgrp * 4 + reg;
            const int rl = labLDS[tr];
            float rowAcc = 0.f;
            #pragma unroll
            for (int ni = 0; ni < 2; ++ni) {
                const int tc = wc * 32 + ni * 16 + lrow;
                float e = __builtin_amdgcn_exp2f(acc[mi][ni][reg] * EXPC);
                float ed = (rl != labLDS[128 + tc]) ? e : 0.f;   // diag auto-excluded
                rowAcc += ed;
                colAcc[ni] += ed;
            }
            #pragma unroll
            for (int off = 1; off < 16; off <<= 1)
                rowAcc += __shfl_xor(rowAcc, off, 64);
            if (lrow == 0) rowD[tr * 4 + wc] = rowAcc;
        }
    }
    #pragma unroll
    for (int ni = 0; ni < 2; ++ni) {
        colAcc[ni] += __shfl_xor(colAcc[ni], 16, 64);
        colAcc[ni] += __shfl_xor(colAcc[ni], 32, 64);
        if (lgrp == 0) {
            const int tc = wc * 32 + ni * 16 + lrow;
            colD[tc * 2 + wr] = colAcc[ni];
        }
    }
    __syncthreads();

    if (tid < 128) {
        pD[(size_t)bj * N_ROWS + rowBase + tid] =
            rowD[tid * 4] + rowD[tid * 4 + 1] + rowD[tid * 4 + 2] + rowD[tid * 4 + 3];
    } else if (tid < 256 && !isDiag) {
        const int c2 = tid - 128;
        pD[(size_t)bi * N_ROWS + colBase + c2] = colD[c2 * 2] + colD[c2 * 2 + 1];
    }
}

// ================= fp8 one-shot 128x128 core (phase3, R11-validated) ========
__device__ __forceinline__ void stage_oneshot(const uchar* __restrict__ xn8,
        const int* __restrict__ perm, int rowBase, int colBase,
        uchar* As, uchar* Bs, int tid)
{
    const int t4 = tid >> 4;
    const int ch = (tid & 15) ^ t4;
    #pragma unroll
    for (int i = 0; i < 8; ++i) {
        const int row = i * 16 + t4;
        int rA = rowBase + row; if (rA > N_ROWS - 1) rA = N_ROWS - 1;
        int rB = colBase + row; if (rB > N_ROWS - 1) rB = N_ROWS - 1;
        const int lds_off = (i * 256 + tid) * 16;
        const uchar* gA = xn8 + (size_t)perm[rA] * KDIM + ch * 16;
        const uchar* gB = xn8 + (size_t)perm[rB] * KDIM + ch * 16;
        __builtin_amdgcn_global_load_lds((const AS1 void*)gA, (AS3 void*)(As + lds_off), 16, 0, 0);
        __builtin_amdgcn_global_load_lds((const AS1 void*)gB, (AS3 void*)(Bs + lds_off), 16, 0, 0);
    }
}

__device__ __forceinline__ void mfma_oneshot(const uchar* As, const uchar* Bs,
        f32x4 (&acc)[4][4], int wave, int lane)
{
    const int wr = wave >> 1, wc = wave & 1;
    const int lrow = lane & 15, kgrp = lane >> 4;
    const int ch2 = kgrp >> 1, half8 = (kgrp & 1) * 8;
    #pragma unroll
    for (int s = 0; s < 8; ++s) {
        const int c16 = s * 2 + ch2;
        i64 a[4], b[4];
        #pragma unroll
        for (int mi = 0; mi < 4; ++mi) {
            const int row = wr*64 + mi*16 + lrow;
            a[mi] = *reinterpret_cast<const i64*>(As + (size_t)row * 256 + ((c16 ^ lrow) * 16) + half8);
        }
        #pragma unroll
        for (int ni = 0; ni < 4; ++ni) {
            const int row = wc*64 + ni*16 + lrow;
            b[ni] = *reinterpret_cast<const i64*>(Bs + (size_t)row * 256 + ((c16 ^ lrow) * 16) + half8);
        }
        #pragma unroll
        for (int mi = 0; mi < 4; ++mi)
            #pragma unroll
            for (int ni = 0; ni < 4; ++ni)
                acc[mi][ni] = __builtin_amdgcn_mfma_f32_16x16x32_fp8_fp8(a[mi], b[ni], acc[mi][ni], 0, 0, 0);
    }
}

__global__ __launch_bounds__(256, 2) void phase3_loss(const uchar* __restrict__ xn8,
        const int* __restrict__ perm, const float* __restrict__ pD,
        const int* __restrict__ classStart, const int* __restrict__ cumTiles,
        float* __restrict__ partial)
{
    __shared__ __align__(16) char pool[65536];
    uchar* As = (uchar*)(pool);
    uchar* Bs = (uchar*)(pool + 32768);
    __shared__ float redF[256];
    __shared__ float DarrH[256];
    __shared__ float DarrR[128];
    __shared__ float DarrC[128];
    __shared__ int   meta[22];

    const int tid = threadIdx.x;
    const int wave = tid >> 6, lane = tid & 63;

    if (tid < 11) { meta[tid] = classStart[tid]; meta[11 + tid] = cumTiles[tid]; }
    __syncthreads();
    const int nTiles = meta[11 + 10];

    float tileSum = 0.f;
    for (int b = blockIdx.x; b < nTiles; b += 512) {
        __syncthreads();   // close previous iteration's LDS use

        int c = 0;
        while (c < 9 && b >= meta[11 + c + 1]) ++c;
        const int s = meta[c], e = meta[c + 1];
        const int nc = e - s;
        const int tps = (nc + 127) >> 7;
        int lt = b - meta[11 + c];
        int ti = 0;
        while (lt >= tps - ti) { lt -= tps - ti; ++ti; }
        const int tj = ti + lt;
        const bool isDiagT = (ti == tj);
        const int rowBase = s + ti * 128, colBase = s + tj * 128;

        // issue tile staging FIRST; latency hides under the gathers
        stage_oneshot(xn8, perm, rowBase, colBase, As, Bs, tid);

        // Darr gather (fixed order)
        {
            int r = rowBase + (tid & 127); if (r > N_ROWS - 1) r = N_ROWS - 1;
            const int half = tid >> 7;
            float d = 0.f;
            #pragma unroll 4
            for (int sl = half * 32; sl < half * 32 + 32; ++sl)
                d += pD[(size_t)sl * N_ROWS + r];
            DarrH[(tid & 127) * 2 + half] = d;
        }
        __syncthreads();
        if (tid < 128) DarrR[tid] = DarrH[tid * 2] + DarrH[tid * 2 + 1];
        __syncthreads();
        if (!isDiagT) {
            int r = colBase + (tid & 127); if (r > N_ROWS - 1) r = N_ROWS - 1;
            const int half = tid >> 7;
            float d = 0.f;
            #pragma unroll 4
            for (int sl = half * 32; sl < half * 32 + 32; ++sl)
                d += pD[(size_t)sl * N_ROWS + r];
            DarrH[(tid & 127) * 2 + half] = d;
            __syncthreads();
            if (tid < 128) DarrC[tid] = DarrH[tid * 2] + DarrH[tid * 2 + 1];
        }
        __syncthreads();   // staging + gathers all complete

        f32x4 acc[4][4] = {};
        mfma_oneshot(As, Bs, acc, wave, lane);

        const int wr = wave >> 1, wc = wave & 1;
        const int lrow = lane & 15, lgrp = lane >> 4;
        #pragma unroll
        for (int mi = 0; mi < 4; ++mi) {
            #pragma unroll
            for (int reg = 0; reg < 4; ++reg) {
                const int tr = wr * 64 + mi * 16 + lgrp * 4 + reg;
                const int r = rowBase + tr;
                if (r < e) {
                    const float Dr = DarrR[tr];
                    #pragma unroll
                    for (int ni = 0; ni < 4; ++ni) {
                        const int tc = wc * 64 + ni * 16 + lrow;
                        const int cg = colBase + tc;
                        if (cg < e) {
                            float sim = acc[mi][ni][reg];
                            float ev = __builtin_amdgcn_exp2f(sim * EXPC);
                            if (isDiagT) {
                                if (cg != r)
                                    tileSum += __logf(ev + Dr) - TEMP_INV * sim;
                            } else {
                                tileSum += __logf(ev + Dr) + __logf(ev + DarrC[tc])
                                         - 2.0f * TEMP_INV * sim;
                            }
                        }
                    }
                }
            }
        }
    }

    __syncthreads();
    redF[tid] = tileSum;
    __syncthreads();
    for (int st = 128; st > 0; st >>= 1) {
        if (tid < st) redF[tid] += redF[tid + st];
        __syncthreads();
    }
    if (tid == 0) partial[blockIdx.x] = redF[0];
}

// ---------------- Kernel 4: deterministic final reduction + scale ----------
__global__ void phase4_final(const float* __restrict__ partial, float* __restrict__ out)
{
    __shared__ float red[256];
    const int tid = threadIdx.x;
    float s = partial[tid] + partial[tid + 256];
    red[tid] = s;
    __syncthreads();
    for (int st = 128; st > 0; st >>= 1) {
        if (tid < st) red[tid] += red[tid + st];
        __syncthreads();
    }
    if (tid == 0) out[0] = red[0] * (1.0f / 16384.0f);
}

extern "C" void kernel_launch(void* const* d_in, const int* in_sizes, int n_in,
                              void* d_out, int out_size, void* d_ws, size_t ws_size,
                              hipStream_t stream)
{
    const float* logits = (const float*)d_in[0];
    const int*   label  = (const int*)d_in[1];
    float* out = (float*)d_out;

    char* ws = (char*)d_ws;
    uchar*  xn8       = (uchar*)(ws);                           // 2 MB
    float*  pD        = (float*)(ws + (2u << 20));              // 2 MB
    int*    perm      = (int*)(ws + (4u << 20));                // 32 KB
    int*    labelPerm = (int*)(ws + (4u << 20) + (32u << 10));  // 32 KB
    int*    classStart= (int*)(ws + (4u << 20) + (64u << 10));  // 64 B
    int*    cumTiles  = (int*)(ws + (4u << 20) + (64u << 10) + 256); // 64 B
    float*  partial   = (float*)(ws + (4u << 20) + (128u << 10));    // 2 KB

    hipLaunchKernelGGL(prep, dim3(2049), dim3(256), 0, stream,
                       logits, label, xn8, perm, labelPerm, classStart, cumTiles);
    hipLaunchKernelGGL(phase1_gemm, dim3(2080), dim3(512), 0, stream,
                       xn8, perm, labelPerm, pD);
    hipLaunchKernelGGL(phase3_loss, dim3(512), dim3(256), 0, stream,
                       xn8, perm, pD, classStart, cumTiles, partial);
    hipLaunchKernelGGL(phase4_final, dim3(1), dim3(256), 0, stream,
                       partial, out);
}

// Round 17
// 72.140 us; speedup vs baseline: 1.1001x; 1.0584x over previous
//
#include <hip/hip_runtime.h>
#include <cstdint>
#include <cstddef>

typedef float  f32x4  __attribute__((ext_vector_type(4)));
typedef long long i64;
typedef unsigned char uchar;

#define N_ROWS 8192
#define KDIM   256
#define TEMP_INV 2.0f
#define LOG2E  1.4426950408889634f
#define EXPC   (TEMP_INV * LOG2E)

#define AS1 __attribute__((address_space(1)))
#define AS3 __attribute__((address_space(3)))

// ---------------- Kernel 1: fused prep (R15/R16-validated) ----------------
__global__ __launch_bounds__(256) void prep(const float* __restrict__ logits,
        const int* __restrict__ label, uchar* __restrict__ xn8,
        int* __restrict__ perm, int* __restrict__ labelPerm,
        int* __restrict__ classStart, int* __restrict__ cumTiles)
{
    __shared__ int lcnt[256][10];
    __shared__ int cstart[11];
    __shared__ int ccount[10];
    const int tid = threadIdx.x;
    const int bid = blockIdx.x;

    if (bid < 2048) {   // normalize path (no perm dependency)
        const int p = bid * 4 + (tid >> 6);
        const int lane = tid & 63;
        float4 v = reinterpret_cast<const float4*>(logits + (size_t)p * KDIM)[lane];
        float ss = v.x*v.x + v.y*v.y + v.z*v.z + v.w*v.w;
        #pragma unroll
        for (int off = 32; off >= 1; off >>= 1) ss += __shfl_xor(ss, off, 64);
        float inv = 1.0f / fmaxf(sqrtf(ss), 1e-8f);
        int pk = __builtin_amdgcn_cvt_pk_fp8_f32(v.x * inv, v.y * inv, 0, false);
        pk     = __builtin_amdgcn_cvt_pk_fp8_f32(v.z * inv, v.w * inv, pk, true);
        reinterpret_cast<unsigned int*>(xn8 + (size_t)p * KDIM)[lane] = (unsigned int)pk;
        return;
    }

    // ---- permutation build (one block, coalesced reads) ----
    const int wave = tid >> 6, lane = tid & 63;
    int lab[32];
    #pragma unroll
    for (int j = 0; j < 32; ++j) {
        int c = label[tid + j * 256];
        lab[j] = (c < 0) ? 0 : (c > 9 ? 9 : c);
    }
    int loc[10] = {0,0,0,0,0,0,0,0,0,0};
    #pragma unroll
    for (int j = 0; j < 32; ++j) loc[lab[j]]++;
    #pragma unroll
    for (int c = 0; c < 10; ++c) lcnt[tid][c] = loc[c];
    __syncthreads();

    for (int c = wave; c < 10; c += 4) {
        int s0 = lcnt[lane*4+0][c], s1 = lcnt[lane*4+1][c];
        int s2 = lcnt[lane*4+2][c], s3 = lcnt[lane*4+3][c];
        int tot = s0 + s1 + s2 + s3;
        int incl = tot;
        #pragma unroll
        for (int d = 1; d < 64; d <<= 1) {
            int up = __shfl_up(incl, d, 64);
            if (lane >= d) incl += up;
        }
        int excl = incl - tot;
        lcnt[lane*4+0][c] = excl;
        lcnt[lane*4+1][c] = excl + s0;
        lcnt[lane*4+2][c] = excl + s0 + s1;
        lcnt[lane*4+3][c] = excl + s0 + s1 + s2;
        if (lane == 63) ccount[c] = incl;
    }
    __syncthreads();

    if (tid == 0) {
        int run = 0, runT = 0;
        for (int c = 0; c < 10; ++c) {
            cstart[c] = run; classStart[c] = run;
            int tpc = (ccount[c] + 127) >> 7;
            cumTiles[c] = runT;
            run  += ccount[c];
            runT += tpc * (tpc + 1) / 2;     // upper-tri within class
        }
        cstart[10] = run; classStart[10] = run; cumTiles[10] = runT;
    }
    __syncthreads();

    int ofs[10];
    #pragma unroll
    for (int c = 0; c < 10; ++c) ofs[c] = lcnt[tid][c];
    #pragma unroll
    for (int j = 0; j < 32; ++j) {
        int c = lab[j];
        int pos = cstart[c] + ofs[c]++;
        perm[pos] = tid + j * 256;
        labelPerm[pos] = c;
    }
}

// ================= fp8 one-shot 128x128 tile core (R11-validated) ===========
// LDS per matrix: 128 rows x 256 B. Stored 16B-chunk slot = c ^ (row&15).
// Rule #21: linear LDS dest, pre-swizzled GLOBAL source, same XOR on ds_read.
__device__ __forceinline__ void stage_mat(const uchar* __restrict__ xn8,
        const int* __restrict__ perm, int base, uchar* dst, int tid)
{
    const int t4 = tid >> 4;
    const int ch = (tid & 15) ^ t4;          // logical chunk, constant per thread
    #pragma unroll
    for (int i = 0; i < 8; ++i) {
        const int row = i * 16 + t4;         // row&15 == t4 for all i
        int r = base + row; if (r > N_ROWS - 1) r = N_ROWS - 1;
        const int lds_off = (i * 256 + tid) * 16;   // wave-uniform base + lane*16
        const uchar* g = xn8 + (size_t)perm[r] * KDIM + ch * 16;
        __builtin_amdgcn_global_load_lds((const AS1 void*)g, (AS3 void*)(dst + lds_off), 16, 0, 0);
    }
}

__device__ __forceinline__ void mfma_oneshot(const uchar* As, const uchar* Bs,
        f32x4 (&acc)[4][4], int wave, int lane)
{
    const int wr = wave >> 1, wc = wave & 1;
    const int lrow = lane & 15, kgrp = lane >> 4;
    const int ch2 = kgrp >> 1, half8 = (kgrp & 1) * 8;
    #pragma unroll
    for (int s = 0; s < 8; ++s) {
        const int c16 = s * 2 + ch2;         // logical 16B chunk for this K=32 step
        i64 a[4], b[4];
        #pragma unroll
        for (int mi = 0; mi < 4; ++mi) {
            const int row = wr*64 + mi*16 + lrow;
            a[mi] = *reinterpret_cast<const i64*>(As + (size_t)row * 256 + ((c16 ^ lrow) * 16) + half8);
        }
        #pragma unroll
        for (int ni = 0; ni < 4; ++ni) {
            const int row = wc*64 + ni*16 + lrow;
            b[ni] = *reinterpret_cast<const i64*>(Bs + (size_t)row * 256 + ((c16 ^ lrow) * 16) + half8);
        }
        #pragma unroll
        for (int mi = 0; mi < 4; ++mi)
            #pragma unroll
            for (int ni = 0; ni < 4; ++ni)
                acc[mi][ni] = __builtin_amdgcn_mfma_f32_16x16x32_fp8_fp8(a[mi], b[ni], acc[mi][ni], 0, 0, 0);
    }
}

// ---------------- Kernel 2: upper-tri 128-tiles (fp8) -> pD partials --------
// pD pre-zeroed by hipMemsetAsync: same-class tiles return WITHOUT stores.
__global__ __launch_bounds__(256, 2) void phase1_gemm(const uchar* __restrict__ xn8,
        const int* __restrict__ perm, const int* __restrict__ labelPerm,
        float* __restrict__ pD)
{
    __shared__ __align__(16) char pool[65536];
    uchar* As = (uchar*)(pool);
    uchar* Bs = (uchar*)(pool + 32768);
    float* rowD = (float*)pool;            // [128][32], aliases pool post-sync
    float* colD = (float*)(pool + 16384);  // [128][8]
    __shared__ int labLDS[256];

    const int tid = threadIdx.x;
    const int wave = tid >> 6, lane = tid & 63;

    int t = blockIdx.x, bi = 0;
    while (t >= 64 - bi) { t -= 64 - bi; ++bi; }
    const int bj = bi + t;
    const bool isDiag = (bi == bj);
    const int rowBase = bi * 128, colBase = bj * 128;

    // class-sorted rows: whole tile same class -> contributes 0 to D.
    // pD is pre-zeroed, so just exit.
    if (labelPerm[rowBase] == labelPerm[colBase + 127]) return;

    stage_mat(xn8, perm, rowBase, As, tid);        // issue early
    if (!isDiag) stage_mat(xn8, perm, colBase, Bs, tid);
    const uchar* Bsrc = isDiag ? As : Bs;
    labLDS[tid] = labelPerm[(tid < 128) ? (rowBase + tid) : (colBase + tid - 128)];
    __syncthreads();                                // one drain

    f32x4 acc[4][4] = {};
    mfma_oneshot(As, Bsrc, acc, wave, lane);
    __syncthreads();                                // release LDS

    const int wr = wave >> 1, wc = wave & 1;
    const int lrow = lane & 15, lgrp = lane >> 4;
    float colAcc[4] = {0.f, 0.f, 0.f, 0.f};
    #pragma unroll
    for (int mi = 0; mi < 4; ++mi) {
        #pragma unroll
        for (int reg = 0; reg < 4; ++reg) {
            const int tr = wr * 64 + mi * 16 + lgrp * 4 + reg;
            const int rl = labLDS[tr];
            float rowAcc = 0.f;
            #pragma unroll
            for (int ni = 0; ni < 4; ++ni) {
                const int tc = wc * 64 + ni * 16 + lrow;
                float e = __builtin_amdgcn_exp2f(acc[mi][ni][reg] * EXPC);
                float ed = (rl != labLDS[128 + tc]) ? e : 0.f;
                rowAcc += ed;
                colAcc[ni] += ed;
            }
            rowD[tr * 32 + wc * 16 + lrow] = rowAcc;
        }
    }
    if (!isDiag) {
        #pragma unroll
        for (int ni = 0; ni < 4; ++ni) {
            const int tc = wc * 64 + ni * 16 + lrow;
            colD[tc * 8 + wr * 4 + lgrp] = colAcc[ni];
        }
    }
    __syncthreads();

    if (tid < 128) {
        const float* p = rowD + tid * 32;
        float s = 0.f;
        #pragma unroll
        for (int k = 0; k < 8; ++k) {
            f32x4 v = *reinterpret_cast<const f32x4*>(p + k * 4);
            s += v[0] + v[1] + v[2] + v[3];
        }
        pD[(size_t)bj * N_ROWS + rowBase + tid] = s;
    } else if (!isDiag) {
        const int c2 = tid - 128;
        const float* p = colD + c2 * 8;
        f32x4 v0 = *reinterpret_cast<const f32x4*>(p);
        f32x4 v1 = *reinterpret_cast<const f32x4*>(p + 4);
        pD[(size_t)bi * N_ROWS + colBase + c2] =
            v0[0] + v0[1] + v0[2] + v0[3] + v1[0] + v1[1] + v1[2] + v1[3];
    }
}

// ---------------- Kernel 3: same-class upper-tri tiles (R11 one-shot) -------
__global__ __launch_bounds__(256, 2) void phase3_loss(const uchar* __restrict__ xn8,
        const int* __restrict__ perm, const float* __restrict__ pD,
        const int* __restrict__ classStart, const int* __restrict__ cumTiles,
        float* __restrict__ partial)
{
    __shared__ __align__(16) char pool[65536];
    uchar* As = (uchar*)(pool);
    uchar* Bs = (uchar*)(pool + 32768);
    __shared__ float redF[256];
    __shared__ float DarrH[256];
    __shared__ float DarrR[128];
    __shared__ float DarrC[128];
    __shared__ int   meta[22];

    const int tid = threadIdx.x;
    const int wave = tid >> 6, lane = tid & 63;

    if (tid < 11) { meta[tid] = classStart[tid]; meta[11 + tid] = cumTiles[tid]; }
    __syncthreads();
    const int nTiles = meta[11 + 10];

    float tileSum = 0.f;
    for (int b = blockIdx.x; b < nTiles; b += 512) {
        __syncthreads();   // close previous iteration's LDS use

        int c = 0;
        while (c < 9 && b >= meta[11 + c + 1]) ++c;
        const int s = meta[c], e = meta[c + 1];
        const int nc = e - s;
        const int tps = (nc + 127) >> 7;
        int lt = b - meta[11 + c];
        int ti = 0;
        while (lt >= tps - ti) { lt -= tps - ti; ++ti; }
        const int tj = ti + lt;
        const bool isDiagT = (ti == tj);
        const int rowBase = s + ti * 128, colBase = s + tj * 128;

        // issue tile staging FIRST; latency hides under the gathers
        stage_mat(xn8, perm, rowBase, As, tid);
        if (!isDiagT) stage_mat(xn8, perm, colBase, Bs, tid);
        const uchar* Bsrc = isDiagT ? As : Bs;

        // Darr gather (fixed order)
        {
            int r = rowBase + (tid & 127); if (r > N_ROWS - 1) r = N_ROWS - 1;
            const int half = tid >> 7;
            float d = 0.f;
            #pragma unroll 4
            for (int sl = half * 32; sl < half * 32 + 32; ++sl)
                d += pD[(size_t)sl * N_ROWS + r];
            DarrH[(tid & 127) * 2 + half] = d;
        }
        __syncthreads();
        if (tid < 128) DarrR[tid] = DarrH[tid * 2] + DarrH[tid * 2 + 1];
        __syncthreads();
        if (!isDiagT) {
            int r = colBase + (tid & 127); if (r > N_ROWS - 1) r = N_ROWS - 1;
            const int half = tid >> 7;
            float d = 0.f;
            #pragma unroll 4
            for (int sl = half * 32; sl < half * 32 + 32; ++sl)
                d += pD[(size_t)sl * N_ROWS + r];
            DarrH[(tid & 127) * 2 + half] = d;
            __syncthreads();
            if (tid < 128) DarrC[tid] = DarrH[tid * 2] + DarrH[tid * 2 + 1];
        }
        __syncthreads();   // staging + gathers all complete

        f32x4 acc[4][4] = {};
        mfma_oneshot(As, Bsrc, acc, wave, lane);

        const int wr = wave >> 1, wc = wave & 1;
        const int lrow = lane & 15, lgrp = lane >> 4;
        #pragma unroll
        for (int mi = 0; mi < 4; ++mi) {
            #pragma unroll
            for (int reg = 0; reg < 4; ++reg) {
                const int tr = wr * 64 + mi * 16 + lgrp * 4 + reg;
                const int r = rowBase + tr;
                if (r < e) {
                    const float Dr = DarrR[tr];
                    #pragma unroll
                    for (int ni = 0; ni < 4; ++ni) {
                        const int tc = wc * 64 + ni * 16 + lrow;
                        const int cg = colBase + tc;
                        if (cg < e) {
                            float sim = acc[mi][ni][reg];
                            float ev = __builtin_amdgcn_exp2f(sim * EXPC);
                            if (isDiagT) {
                                if (cg != r)
                                    tileSum += __logf(ev + Dr) - TEMP_INV * sim;
                            } else {
                                tileSum += __logf(ev + Dr) + __logf(ev + DarrC[tc])
                                         - 2.0f * TEMP_INV * sim;
                            }
                        }
                    }
                }
            }
        }
    }

    __syncthreads();
    redF[tid] = tileSum;
    __syncthreads();
    for (int st = 128; st > 0; st >>= 1) {
        if (tid < st) redF[tid] += redF[tid + st];
        __syncthreads();
    }
    if (tid == 0) partial[blockIdx.x] = redF[0];
}

// ---------------- Kernel 4: deterministic final reduction + scale ----------
__global__ void phase4_final(const float* __restrict__ partial, float* __restrict__ out)
{
    __shared__ float red[256];
    const int tid = threadIdx.x;
    float s = partial[tid] + partial[tid + 256];
    red[tid] = s;
    __syncthreads();
    for (int st = 128; st > 0; st >>= 1) {
        if (tid < st) red[tid] += red[tid + st];
        __syncthreads();
    }
    if (tid == 0) out[0] = red[0] * (1.0f / 16384.0f);
}

extern "C" void kernel_launch(void* const* d_in, const int* in_sizes, int n_in,
                              void* d_out, int out_size, void* d_ws, size_t ws_size,
                              hipStream_t stream)
{
    const float* logits = (const float*)d_in[0];
    const int*   label  = (const int*)d_in[1];
    float* out = (float*)d_out;

    char* ws = (char*)d_ws;
    uchar*  xn8       = (uchar*)(ws);                           // 2 MB
    float*  pD        = (float*)(ws + (2u << 20));              // 2 MB
    int*    perm      = (int*)(ws + (4u << 20));                // 32 KB
    int*    labelPerm = (int*)(ws + (4u << 20) + (32u << 10));  // 32 KB
    int*    classStart= (int*)(ws + (4u << 20) + (64u << 10));  // 64 B
    int*    cumTiles  = (int*)(ws + (4u << 20) + (64u << 10) + 256); // 64 B
    float*  partial   = (float*)(ws + (4u << 20) + (128u << 10));    // 2 KB

    hipMemsetAsync(pD, 0, (size_t)64 * N_ROWS * sizeof(float), stream);
    hipLaunchKernelGGL(prep, dim3(2049), dim3(256), 0, stream,
                       logits, label, xn8, perm, labelPerm, classStart, cumTiles);
    hipLaunchKernelGGL(phase1_gemm, dim3(2080), dim3(256), 0, stream,
                       xn8, perm, labelPerm, pD);
    hipLaunchKernelGGL(phase3_loss, dim3(512), dim3(256), 0, stream,
                       xn8, perm, pD, classStart, cumTiles, partial);
    hipLaunchKernelGGL(phase4_final, dim3(1), dim3(256), 0, stream,
                       partial, out);
}

// Round 18
// 67.808 us; speedup vs baseline: 1.1703x; 1.0639x over previous
//
#include <hip/hip_runtime.h>
#include <cstdint>
#include <cstddef>

typedef float  f32x4  __attribute__((ext_vector_type(4)));
typedef long long i64;
typedef unsigned char uchar;

#define N_ROWS 8192
#define KDIM   256
#define TEMP_INV 2.0f
#define LOG2E  1.4426950408889634f
#define EXPC   (TEMP_INV * LOG2E)

#define AS1 __attribute__((address_space(1)))
#define AS3 __attribute__((address_space(3)))

// ---------------- Kernel 1: fused prep (R10/R11-validated, 68.1us config) ---
// Blocks 0..2047: normalize+fp8-cast rows UNPERMUTED. Block 2048: build perm.
__global__ __launch_bounds__(256) void prep(const float* __restrict__ logits,
        const int* __restrict__ label, uchar* __restrict__ xn8,
        int* __restrict__ perm, int* __restrict__ labelPerm,
        int* __restrict__ classStart, int* __restrict__ cumTiles)
{
    __shared__ int lcnt[256][10];
    __shared__ int cstart[11];
    __shared__ int ccount[10];
    const int tid = threadIdx.x;
    const int bid = blockIdx.x;

    if (bid < 2048) {   // normalize path (no perm dependency)
        const int p = bid * 4 + (tid >> 6);
        const int lane = tid & 63;
        float4 v = reinterpret_cast<const float4*>(logits + (size_t)p * KDIM)[lane];
        float ss = v.x*v.x + v.y*v.y + v.z*v.z + v.w*v.w;
        #pragma unroll
        for (int off = 32; off >= 1; off >>= 1) ss += __shfl_xor(ss, off, 64);
        float inv = 1.0f / fmaxf(sqrtf(ss), 1e-8f);
        int pk = __builtin_amdgcn_cvt_pk_fp8_f32(v.x * inv, v.y * inv, 0, false);
        pk     = __builtin_amdgcn_cvt_pk_fp8_f32(v.z * inv, v.w * inv, pk, true);
        reinterpret_cast<unsigned int*>(xn8 + (size_t)p * KDIM)[lane] = (unsigned int)pk;
        return;
    }

    // ---- permutation build (one block) ----
    const int wave = tid >> 6, lane = tid & 63;
    const int beg = tid * 32, end = beg + 32;
    int loc[10] = {0,0,0,0,0,0,0,0,0,0};
    for (int i = beg; i < end; ++i) {
        int c = label[i]; c = (c < 0) ? 0 : (c > 9 ? 9 : c);
        loc[c]++;
    }
    #pragma unroll
    for (int c = 0; c < 10; ++c) lcnt[tid][c] = loc[c];
    __syncthreads();

    for (int c = wave; c < 10; c += 4) {
        int s0 = lcnt[lane*4+0][c], s1 = lcnt[lane*4+1][c];
        int s2 = lcnt[lane*4+2][c], s3 = lcnt[lane*4+3][c];
        int tot = s0 + s1 + s2 + s3;
        int incl = tot;
        #pragma unroll
        for (int d = 1; d < 64; d <<= 1) {
            int up = __shfl_up(incl, d, 64);
            if (lane >= d) incl += up;
        }
        int excl = incl - tot;
        lcnt[lane*4+0][c] = excl;
        lcnt[lane*4+1][c] = excl + s0;
        lcnt[lane*4+2][c] = excl + s0 + s1;
        lcnt[lane*4+3][c] = excl + s0 + s1 + s2;
        if (lane == 63) ccount[c] = incl;
    }
    __syncthreads();

    if (tid == 0) {
        int run = 0, runT = 0;
        for (int c = 0; c < 10; ++c) {
            cstart[c] = run; classStart[c] = run;
            int tpc = (ccount[c] + 127) >> 7;
            cumTiles[c] = runT;
            run  += ccount[c];
            runT += tpc * (tpc + 1) / 2;     // upper-tri within class
        }
        cstart[10] = run; classStart[10] = run; cumTiles[10] = runT;
    }
    __syncthreads();

    int ofs[10];
    #pragma unroll
    for (int c = 0; c < 10; ++c) ofs[c] = lcnt[tid][c];
    for (int i = beg; i < end; ++i) {
        int c = label[i]; c = (c < 0) ? 0 : (c > 9 ? 9 : c);
        int pos = cstart[c] + ofs[c]++;
        perm[pos] = i;
        labelPerm[pos] = c;
    }
}

// ================= fp8 one-shot 128x128 tile core (K=256 fully staged) ======
// LDS per matrix: 128 rows x 256 B. Stored 16B-chunk slot = c ^ (row&15).
// Rule #21: linear LDS dest, pre-swizzled GLOBAL source, same XOR on ds_read.
__device__ __forceinline__ void stage_oneshot(const uchar* __restrict__ xn8,
        const int* __restrict__ perm, int rowBase, int colBase,
        uchar* As, uchar* Bs, int tid)
{
    const int t4 = tid >> 4;
    const int ch = (tid & 15) ^ t4;          // logical chunk, constant per thread
    #pragma unroll
    for (int i = 0; i < 8; ++i) {
        const int row = i * 16 + t4;         // row&15 == t4 for all i
        int rA = rowBase + row; if (rA > N_ROWS - 1) rA = N_ROWS - 1;
        int rB = colBase + row; if (rB > N_ROWS - 1) rB = N_ROWS - 1;
        const int lds_off = (i * 256 + tid) * 16;   // wave-uniform base + lane*16
        const uchar* gA = xn8 + (size_t)perm[rA] * KDIM + ch * 16;
        const uchar* gB = xn8 + (size_t)perm[rB] * KDIM + ch * 16;
        __builtin_amdgcn_global_load_lds((const AS1 void*)gA, (AS3 void*)(As + lds_off), 16, 0, 0);
        __builtin_amdgcn_global_load_lds((const AS1 void*)gB, (AS3 void*)(Bs + lds_off), 16, 0, 0);
    }
}

__device__ __forceinline__ void mfma_oneshot(const uchar* As, const uchar* Bs,
        f32x4 (&acc)[4][4], int wave, int lane)
{
    const int wr = wave >> 1, wc = wave & 1;
    const int lrow = lane & 15, kgrp = lane >> 4;
    const int ch2 = kgrp >> 1, half8 = (kgrp & 1) * 8;
    #pragma unroll
    for (int s = 0; s < 8; ++s) {
        const int c16 = s * 2 + ch2;         // logical 16B chunk for this K=32 step
        i64 a[4], b[4];
        #pragma unroll
        for (int mi = 0; mi < 4; ++mi) {
            const int row = wr*64 + mi*16 + lrow;
            a[mi] = *reinterpret_cast<const i64*>(As + (size_t)row * 256 + ((c16 ^ lrow) * 16) + half8);
        }
        #pragma unroll
        for (int ni = 0; ni < 4; ++ni) {
            const int row = wc*64 + ni*16 + lrow;
            b[ni] = *reinterpret_cast<const i64*>(Bs + (size_t)row * 256 + ((c16 ^ lrow) * 16) + half8);
        }
        #pragma unroll
        for (int mi = 0; mi < 4; ++mi)
            #pragma unroll
            for (int ni = 0; ni < 4; ++ni)
                acc[mi][ni] = __builtin_amdgcn_mfma_f32_16x16x32_fp8_fp8(a[mi], b[ni], acc[mi][ni], 0, 0, 0);
    }
}

// ---------------- Kernel 2: upper-tri 128-tiles (fp8) -> pD partials --------
__global__ __launch_bounds__(256, 2) void phase1_gemm(const uchar* __restrict__ xn8,
        const int* __restrict__ perm, const int* __restrict__ labelPerm,
        float* __restrict__ pD)
{
    __shared__ __align__(16) char pool[65536];
    uchar* As = (uchar*)(pool);
    uchar* Bs = (uchar*)(pool + 32768);
    float* rowD = (float*)pool;            // [128][32], aliases pool post-sync
    float* colD = (float*)(pool + 16384);  // [128][8]
    __shared__ int labLDS[256];

    const int tid = threadIdx.x;
    const int wave = tid >> 6, lane = tid & 63;

    int t = blockIdx.x, bi = 0;
    while (t >= 64 - bi) { t -= 64 - bi; ++bi; }
    const int bj = bi + t;
    const bool isDiag = (bi == bj);
    const int rowBase = bi * 128, colBase = bj * 128;

    // class-sorted rows: whole tile same class -> contributes 0 to D
    if (labelPerm[rowBase] == labelPerm[colBase + 127]) {
        if (tid < 128)       pD[(size_t)bj * N_ROWS + rowBase + tid] = 0.f;
        else if (!isDiag)    pD[(size_t)bi * N_ROWS + colBase + tid - 128] = 0.f;
        return;
    }

    stage_oneshot(xn8, perm, rowBase, colBase, As, Bs, tid);   // issue early
    labLDS[tid] = labelPerm[(tid < 128) ? (rowBase + tid) : (colBase + tid - 128)];
    __syncthreads();                                            // one drain

    f32x4 acc[4][4] = {};
    mfma_oneshot(As, Bs, acc, wave, lane);
    __syncthreads();                                            // release LDS

    const int wr = wave >> 1, wc = wave & 1;
    const int lrow = lane & 15, lgrp = lane >> 4;
    float colAcc[4] = {0.f, 0.f, 0.f, 0.f};
    #pragma unroll
    for (int mi = 0; mi < 4; ++mi) {
        #pragma unroll
        for (int reg = 0; reg < 4; ++reg) {
            const int tr = wr * 64 + mi * 16 + lgrp * 4 + reg;
            const int rl = labLDS[tr];
            float rowAcc = 0.f;
            #pragma unroll
            for (int ni = 0; ni < 4; ++ni) {
                const int tc = wc * 64 + ni * 16 + lrow;
                float e = __builtin_amdgcn_exp2f(acc[mi][ni][reg] * EXPC);
                float ed = (rl != labLDS[128 + tc]) ? e : 0.f;
                rowAcc += ed;
                colAcc[ni] += ed;
            }
            rowD[tr * 32 + wc * 16 + lrow] = rowAcc;
        }
    }
    if (!isDiag) {
        #pragma unroll
        for (int ni = 0; ni < 4; ++ni) {
            const int tc = wc * 64 + ni * 16 + lrow;
            colD[tc * 8 + wr * 4 + lgrp] = colAcc[ni];
        }
    }
    __syncthreads();

    if (tid < 128) {
        const float* p = rowD + tid * 32;
        float s = 0.f;
        #pragma unroll
        for (int k = 0; k < 8; ++k) {
            f32x4 v = *reinterpret_cast<const f32x4*>(p + k * 4);
            s += v[0] + v[1] + v[2] + v[3];
        }
        pD[(size_t)bj * N_ROWS + rowBase + tid] = s;
    } else if (!isDiag) {
        const int c2 = tid - 128;
        const float* p = colD + c2 * 8;
        f32x4 v0 = *reinterpret_cast<const f32x4*>(p);
        f32x4 v1 = *reinterpret_cast<const f32x4*>(p + 4);
        pD[(size_t)bi * N_ROWS + colBase + c2] =
            v0[0] + v0[1] + v0[2] + v0[3] + v1[0] + v1[1] + v1[2] + v1[3];
    }
}

// ---------------- Kernel 3: same-class upper-tri tiles (one-shot core) ------
__global__ __launch_bounds__(256, 2) void phase3_loss(const uchar* __restrict__ xn8,
        const int* __restrict__ perm, const float* __restrict__ pD,
        const int* __restrict__ classStart, const int* __restrict__ cumTiles,
        float* __restrict__ partial)
{
    __shared__ __align__(16) char pool[65536];
    uchar* As = (uchar*)(pool);
    uchar* Bs = (uchar*)(pool + 32768);
    __shared__ float redF[256];
    __shared__ float DarrH[256];
    __shared__ float DarrR[128];
    __shared__ float DarrC[128];
    __shared__ int   meta[22];

    const int tid = threadIdx.x;
    const int wave = tid >> 6, lane = tid & 63;

    if (tid < 11) { meta[tid] = classStart[tid]; meta[11 + tid] = cumTiles[tid]; }
    __syncthreads();
    const int nTiles = meta[11 + 10];

    float tileSum = 0.f;
    for (int b = blockIdx.x; b < nTiles; b += 512) {
        __syncthreads();   // close previous iteration's LDS use

        int c = 0;
        while (c < 9 && b >= meta[11 + c + 1]) ++c;
        const int s = meta[c], e = meta[c + 1];
        const int nc = e - s;
        const int tps = (nc + 127) >> 7;
        int lt = b - meta[11 + c];
        int ti = 0;
        while (lt >= tps - ti) { lt -= tps - ti; ++ti; }
        const int tj = ti + lt;
        const bool isDiagT = (ti == tj);
        const int rowBase = s + ti * 128, colBase = s + tj * 128;

        // issue tile staging FIRST; latency hides under the gathers
        stage_oneshot(xn8, perm, rowBase, colBase, As, Bs, tid);

        // Darr gather (fixed order)
        {
            int r = rowBase + (tid & 127); if (r > N_ROWS - 1) r = N_ROWS - 1;
            const int half = tid >> 7;
            float d = 0.f;
            #pragma unroll 4
            for (int sl = half * 32; sl < half * 32 + 32; ++sl)
                d += pD[(size_t)sl * N_ROWS + r];
            DarrH[(tid & 127) * 2 + half] = d;
        }
        __syncthreads();
        if (tid < 128) DarrR[tid] = DarrH[tid * 2] + DarrH[tid * 2 + 1];
        __syncthreads();
        if (!isDiagT) {
            int r = colBase + (tid & 127); if (r > N_ROWS - 1) r = N_ROWS - 1;
            const int half = tid >> 7;
            float d = 0.f;
            #pragma unroll 4
            for (int sl = half * 32; sl < half * 32 + 32; ++sl)
                d += pD[(size_t)sl * N_ROWS + r];
            DarrH[(tid & 127) * 2 + half] = d;
            __syncthreads();
            if (tid < 128) DarrC[tid] = DarrH[tid * 2] + DarrH[tid * 2 + 1];
        }
        __syncthreads();   // staging + gathers all complete

        f32x4 acc[4][4] = {};
        mfma_oneshot(As, Bs, acc, wave, lane);

        const int wr = wave >> 1, wc = wave & 1;
        const int lrow = lane & 15, lgrp = lane >> 4;
        #pragma unroll
        for (int mi = 0; mi < 4; ++mi) {
            #pragma unroll
            for (int reg = 0; reg < 4; ++reg) {
                const int tr = wr * 64 + mi * 16 + lgrp * 4 + reg;
                const int r = rowBase + tr;
                if (r < e) {
                    const float Dr = DarrR[tr];
                    #pragma unroll
                    for (int ni = 0; ni < 4; ++ni) {
                        const int tc = wc * 64 + ni * 16 + lrow;
                        const int cg = colBase + tc;
                        if (cg < e) {
                            float sim = acc[mi][ni][reg];
                            float ev = __builtin_amdgcn_exp2f(sim * EXPC);
                            if (isDiagT) {
                                if (cg != r)
                                    tileSum += __logf(ev + Dr) - TEMP_INV * sim;
                            } else {
                                tileSum += __logf(ev + Dr) + __logf(ev + DarrC[tc])
                                         - 2.0f * TEMP_INV * sim;
                            }
                        }
                    }
                }
            }
        }
    }

    __syncthreads();
    redF[tid] = tileSum;
    __syncthreads();
    for (int st = 128; st > 0; st >>= 1) {
        if (tid < st) redF[tid] += redF[tid + st];
        __syncthreads();
    }
    if (tid == 0) partial[blockIdx.x] = redF[0];
}

// ---------------- Kernel 4: deterministic final reduction + scale ----------
__global__ void phase4_final(const float* __restrict__ partial, float* __restrict__ out)
{
    __shared__ float red[256];
    const int tid = threadIdx.x;
    float s = partial[tid] + partial[tid + 256];
    red[tid] = s;
    __syncthreads();
    for (int st = 128; st > 0; st >>= 1) {
        if (tid < st) red[tid] += red[tid + st];
        __syncthreads();
    }
    if (tid == 0) out[0] = red[0] * (1.0f / 16384.0f);
}

extern "C" void kernel_launch(void* const* d_in, const int* in_sizes, int n_in,
                              void* d_out, int out_size, void* d_ws, size_t ws_size,
                              hipStream_t stream)
{
    const float* logits = (const float*)d_in[0];
    const int*   label  = (const int*)d_in[1];
    float* out = (float*)d_out;

    char* ws = (char*)d_ws;
    uchar*  xn8       = (uchar*)(ws);                           // 2 MB
    float*  pD        = (float*)(ws + (2u << 20));              // 2 MB
    int*    perm      = (int*)(ws + (4u << 20));                // 32 KB
    int*    labelPerm = (int*)(ws + (4u << 20) + (32u << 10));  // 32 KB
    int*    classStart= (int*)(ws + (4u << 20) + (64u << 10));  // 64 B
    int*    cumTiles  = (int*)(ws + (4u << 20) + (64u << 10) + 256); // 64 B
    float*  partial   = (float*)(ws + (4u << 20) + (128u << 10));    // 2 KB

    hipLaunchKernelGGL(prep, dim3(2049), dim3(256), 0, stream,
                       logits, label, xn8, perm, labelPerm, classStart, cumTiles);
    hipLaunchKernelGGL(phase1_gemm, dim3(2080), dim3(256), 0, stream,
                       xn8, perm, labelPerm, pD);
    hipLaunchKernelGGL(phase3_loss, dim3(512), dim3(256), 0, stream,
                       xn8, perm, pD, classStart, cumTiles, partial);
    hipLaunchKernelGGL(phase4_final, dim3(1), dim3(256), 0, stream,
                       partial, out);
}